// Round 2
// baseline (349.073 us; speedup 1.0000x reference)
//
#include <hip/hip_runtime.h>

typedef float f32x4 __attribute__((ext_vector_type(4)));
typedef short s16x4 __attribute__((ext_vector_type(4)));
typedef short s16x8 __attribute__((ext_vector_type(8)));

#define SA 136   // row stride (shorts) for 64x128 row-major bf16 tiles (16B-mult)
#define ST 72    // row stride (shorts) for transposed [d][key] tiles (16B-mult)

__device__ __forceinline__ short f2bf(float f) {
    union { float f; unsigned u; } c; c.f = f;
    return (short)((c.u + 0x7FFFu + ((c.u >> 16) & 1u)) >> 16);
}

// ---- prep: transpose 5 fp32 [k][n] weights into bf16 [n][k] in workspace ----
__global__ __launch_bounds__(256) void k_prep(
    const float* __restrict__ Wq, const float* __restrict__ Wk,
    const float* __restrict__ Wv, const float* __restrict__ Wot,
    const float* __restrict__ Wtg, short* __restrict__ Wt) {
    const float* srcs[5] = {Wq, Wk, Wv, Wot, Wtg};
    const float* W = srcs[blockIdx.x];
    short* dst = Wt + blockIdx.x * 16384;
    const int t = threadIdx.x;
#pragma unroll 4
    for (int i = 0; i < 64; ++i) {
        int idx = i * 256 + t;
        int k = idx >> 7, n = idx & 127;
        dst[n * 128 + k] = f2bf(W[idx]);
    }
}

// B-fragment from pre-transposed bf16 weight: Wt[n][k], n=ni*16+m, k=kk*32+quad*8
__device__ __forceinline__ s16x8 wfrag(const short* __restrict__ Wt,
                                       int ni, int kk, int m, int quad) {
    return *(const s16x8*)(Wt + (ni * 16 + m) * 128 + kk * 32 + quad * 8);
}

__global__ __launch_bounds__(256) void k_main(
    const float* __restrict__ XQ, const float* __restrict__ XK,
    const float* __restrict__ Tgt, const short* __restrict__ Wt,
    const float* __restrict__ bq, const float* __restrict__ bk,
    const float* __restrict__ bv, const float* __restrict__ bot,
    const float* __restrict__ btg,
    const float* __restrict__ g_time, const float* __restrict__ b_time,
    const float* __restrict__ g_tgt, const float* __restrict__ b_tgt,
    float* __restrict__ out0, float* __restrict__ out1, float* __restrict__ out2) {
    const int bn = blockIdx.x;
    const int t = threadIdx.x;
    const int w = t >> 6, lane = t & 63, m = lane & 15, quad = lane >> 4;

    __shared__ short R1[64 * SA];   // XQ stage -> q -> tv        (17408 B)
    __shared__ short R2[64 * SA];   // k -> ct                    (17408 B)
    __shared__ short R3[128 * ST];  // XK stage -> v^T            (18432 B)
    __shared__ short R4[64 * ST];   // S (bf16, A-layout)         ( 9216 B)
    __shared__ short R5[16 * ST];   // Tgt^T per-head slice       ( 2304 B)

    const size_t base = (size_t)bn * 8192;
    const short* Wqt = Wt;
    const short* Wkt = Wt + 16384;
    const short* Wvt = Wt + 32768;
    const short* Wot_t = Wt + 49152;
    const short* Wtg_t = Wt + 65536;

    // ---------- stage XK (fp32 -> bf16) into R3 used row-major stride SA ----
    {
        const float* src = XK + base;
#pragma unroll
        for (int it = 0; it < 8; ++it) {
            int e = t + it * 256;  // float4 index
            f32x4 x = *(const f32x4*)(src + e * 4);
            int row = e >> 5, col = (e & 31) * 4;
            s16x4 p; p[0] = f2bf(x[0]); p[1] = f2bf(x[1]);
            p[2] = f2bf(x[2]); p[3] = f2bf(x[3]);
            *(s16x4*)(R3 + row * SA + col) = p;
        }
    }
    __syncthreads();

    // ---------- k = XK@Wk + bk  -> R2 row-major; v frags kept in regs -------
    {
        s16x8 a[4];
#pragma unroll
        for (int kk = 0; kk < 4; ++kk)
            a[kk] = *(const s16x8*)(R3 + (w * 16 + m) * SA + kk * 32 + quad * 8);

        f32x4 acck[8], accv[8];
#pragma unroll
        for (int ni = 0; ni < 8; ++ni) {
            acck[ni] = (f32x4){0.f, 0.f, 0.f, 0.f};
            accv[ni] = (f32x4){0.f, 0.f, 0.f, 0.f};
#pragma unroll
            for (int kk = 0; kk < 4; ++kk) {
                acck[ni] = __builtin_amdgcn_mfma_f32_16x16x32_bf16(
                    a[kk], wfrag(Wkt, ni, kk, m, quad), acck[ni], 0, 0, 0);
                accv[ni] = __builtin_amdgcn_mfma_f32_16x16x32_bf16(
                    a[kk], wfrag(Wvt, ni, kk, m, quad), accv[ni], 0, 0, 0);
            }
        }
        // write k (own 16-row band; nobody reads R2 yet)
#pragma unroll
        for (int ni = 0; ni < 8; ++ni) {
            const float bb = bk[ni * 16 + m];
#pragma unroll
            for (int r = 0; r < 4; ++r)
                R2[(w * 16 + quad * 4 + r) * SA + ni * 16 + m] = f2bf(acck[ni][r] + bb);
        }
        __syncthreads();  // all waves done reading XK tile in R3
        // write v transposed into R3: svT[d][key]
#pragma unroll
        for (int ni = 0; ni < 8; ++ni) {
            const float bb = bv[ni * 16 + m];
#pragma unroll
            for (int r = 0; r < 4; ++r)
                R3[(ni * 16 + m) * ST + w * 16 + quad * 4 + r] = f2bf(accv[ni][r] + bb);
        }
    }

    // ---------- stage XQ into R1, q = XQ@Wq + bq -> overwrite R1 ------------
    {
        const float* src = XQ + base;
#pragma unroll
        for (int it = 0; it < 8; ++it) {
            int e = t + it * 256;
            f32x4 x = *(const f32x4*)(src + e * 4);
            int row = e >> 5, col = (e & 31) * 4;
            s16x4 p; p[0] = f2bf(x[0]); p[1] = f2bf(x[1]);
            p[2] = f2bf(x[2]); p[3] = f2bf(x[3]);
            *(s16x4*)(R1 + row * SA + col) = p;
        }
    }
    __syncthreads();
    {
        s16x8 a[4];
#pragma unroll
        for (int kk = 0; kk < 4; ++kk)
            a[kk] = *(const s16x8*)(R1 + (w * 16 + m) * SA + kk * 32 + quad * 8);
        f32x4 accq[8];
#pragma unroll
        for (int ni = 0; ni < 8; ++ni) {
            accq[ni] = (f32x4){0.f, 0.f, 0.f, 0.f};
#pragma unroll
            for (int kk = 0; kk < 4; ++kk)
                accq[ni] = __builtin_amdgcn_mfma_f32_16x16x32_bf16(
                    a[kk], wfrag(Wqt, ni, kk, m, quad), accq[ni], 0, 0, 0);
        }
        __syncthreads();  // everyone's staged-XQ reads complete
#pragma unroll
        for (int ni = 0; ni < 8; ++ni) {
            const float bb = bq[ni * 16 + m];
#pragma unroll
            for (int r = 0; r < 4; ++r)
                R1[(w * 16 + quad * 4 + r) * SA + ni * 16 + m] = f2bf(accq[ni][r] + bb);
        }
    }
    __syncthreads();  // q in R1, k in R2, v^T in R3 all visible

    // ---------- per-head: S = q k^T / 4 ; tv += S v ; ct += S tk ------------
    f32x4 accv8[8], acct8[8];
    const s16x8 zfrag = (s16x8){0, 0, 0, 0, 0, 0, 0, 0};
#pragma unroll
    for (int h = 0; h < 8; ++h) {
        // stage Tgt^T slice for this head (all threads)
        {
            int key = t >> 2, c0 = (t & 3) * 4;
            f32x4 x = *(const f32x4*)(Tgt + base + key * 128 + h * 16 + c0);
#pragma unroll
            for (int r = 0; r < 4; ++r) R5[(c0 + r) * ST + key] = f2bf(x[r]);
        }
        __syncthreads();

        // S for this wave's 16-row band (K=32 MFMA, upper 16 k zeroed)
        s16x8 aq = zfrag;
        if (quad < 2)
            aq = *(const s16x8*)(R1 + (w * 16 + m) * SA + h * 16 + quad * 8);
#pragma unroll
        for (int nj = 0; nj < 4; ++nj) {
            s16x8 bk_ = zfrag;
            if (quad < 2)
                bk_ = *(const s16x8*)(R2 + (nj * 16 + m) * SA + h * 16 + quad * 8);
            f32x4 s = __builtin_amdgcn_mfma_f32_16x16x32_bf16(
                aq, bk_, (f32x4){0.f, 0.f, 0.f, 0.f}, 0, 0, 0);
#pragma unroll
            for (int r = 0; r < 4; ++r) {
                const int row = w * 16 + quad * 4 + r;
                const float sval = s[r] * 0.25f;
                out0[(size_t)bn * 32768 + h * 4096 + row * 64 + nj * 16 + m] = sval;
                R4[row * ST + nj * 16 + m] = f2bf(sval);
            }
        }

        // tv_h = S @ v_h ; ct_h = S @ tk_h   (S read back from R4, own band)
        accv8[h] = (f32x4){0.f, 0.f, 0.f, 0.f};
        acct8[h] = (f32x4){0.f, 0.f, 0.f, 0.f};
#pragma unroll
        for (int kk = 0; kk < 2; ++kk) {
            s16x8 a  = *(const s16x8*)(R4 + (w * 16 + m) * ST + kk * 32 + quad * 8);
            s16x8 bv_ = *(const s16x8*)(R3 + (h * 16 + m) * ST + kk * 32 + quad * 8);
            s16x8 bt_ = *(const s16x8*)(R5 + m * ST + kk * 32 + quad * 8);
            accv8[h] = __builtin_amdgcn_mfma_f32_16x16x32_bf16(a, bv_, accv8[h], 0, 0, 0);
            acct8[h] = __builtin_amdgcn_mfma_f32_16x16x32_bf16(a, bt_, acct8[h], 0, 0, 0);
        }
        __syncthreads();  // protect R5 (next head) + final R1/R2 reuse
    }

    // ---------- write tv -> R1, ct -> R2 (A-layout, bf16) -------------------
#pragma unroll
    for (int h = 0; h < 8; ++h) {
#pragma unroll
        for (int r = 0; r < 4; ++r) {
            const int row = w * 16 + quad * 4 + r;
            R1[row * SA + h * 16 + m] = f2bf(accv8[h][r]);
            R2[row * SA + h * 16 + m] = f2bf(acct8[h][r]);
        }
    }
    __syncthreads();

    // ---------- output projections + LayerNorm ------------------------------
#pragma unroll
    for (int br = 0; br < 2; ++br) {
        const short* sA = br == 0 ? R1 : R2;
        const short* Wp = br == 0 ? Wot_t : Wtg_t;
        const float* bias = br == 0 ? bot : btg;
        const float* gam = br == 0 ? g_time : g_tgt;
        const float* bet = br == 0 ? b_time : b_tgt;
        float* outp = (br == 0 ? out1 : out2) + base;
        const float* resid = br == 0 ? XQ + base : nullptr;

        s16x8 a[4];
#pragma unroll
        for (int kk = 0; kk < 4; ++kk)
            a[kk] = *(const s16x8*)(sA + (w * 16 + m) * SA + kk * 32 + quad * 8);
        f32x4 acc[8];
#pragma unroll
        for (int ni = 0; ni < 8; ++ni) {
            acc[ni] = (f32x4){0.f, 0.f, 0.f, 0.f};
#pragma unroll
            for (int kk = 0; kk < 4; ++kk)
                acc[ni] = __builtin_amdgcn_mfma_f32_16x16x32_bf16(
                    a[kk], wfrag(Wp, ni, kk, m, quad), acc[ni], 0, 0, 0);
        }
        float y[8][4];
        float s1[4] = {0.f, 0.f, 0.f, 0.f}, s2[4] = {0.f, 0.f, 0.f, 0.f};
#pragma unroll
        for (int ni = 0; ni < 8; ++ni) {
            const int col = ni * 16 + m;
            const float bb = bias[col];
#pragma unroll
            for (int r = 0; r < 4; ++r) {
                const int row = w * 16 + quad * 4 + r;
                float v = acc[ni][r] + bb;
                if (resid) v += resid[row * 128 + col];
                y[ni][r] = v;
                s1[r] += v;
                s2[r] += v * v;
            }
        }
#pragma unroll
        for (int mask = 1; mask < 16; mask <<= 1) {
#pragma unroll
            for (int r = 0; r < 4; ++r) {
                s1[r] += __shfl_xor(s1[r], mask, 64);
                s2[r] += __shfl_xor(s2[r], mask, 64);
            }
        }
        float mu[4], rstd[4];
#pragma unroll
        for (int r = 0; r < 4; ++r) {
            mu[r] = s1[r] * (1.0f / 128.0f);
            float var = s2[r] * (1.0f / 128.0f) - mu[r] * mu[r];
            rstd[r] = rsqrtf(var + 1e-5f);
        }
#pragma unroll
        for (int ni = 0; ni < 8; ++ni) {
            const int col = ni * 16 + m;
            const float g = gam[col], bb = bet[col];
#pragma unroll
            for (int r = 0; r < 4; ++r) {
                const int row = w * 16 + quad * 4 + r;
                outp[row * 128 + col] = (y[ni][r] - mu[r]) * rstd[r] * g + bb;
            }
        }
    }
}

extern "C" void kernel_launch(void* const* d_in, const int* in_sizes, int n_in,
                              void* d_out, int out_size, void* d_ws, size_t ws_size,
                              hipStream_t stream) {
    const float* XQ  = (const float*)d_in[0];
    const float* XK  = (const float*)d_in[1];
    const float* Tgt = (const float*)d_in[2];
    const float* Wq  = (const float*)d_in[3];
    const float* bq  = (const float*)d_in[4];
    const float* Wk  = (const float*)d_in[5];
    const float* bk  = (const float*)d_in[6];
    const float* Wv  = (const float*)d_in[7];
    const float* bv  = (const float*)d_in[8];
    const float* Wot = (const float*)d_in[9];
    const float* bot = (const float*)d_in[10];
    const float* Wtg = (const float*)d_in[11];
    const float* btg = (const float*)d_in[12];
    const float* g_time = (const float*)d_in[13];
    const float* b_time = (const float*)d_in[14];
    const float* g_tgt  = (const float*)d_in[15];
    const float* b_tgt  = (const float*)d_in[16];

    const int BN = in_sizes[0] / 8192;  // B*N

    short* Wt = (short*)d_ws;  // 5 * 128 * 128 bf16 = 160 KB

    float* out0 = (float*)d_out;
    float* out1 = out0 + (size_t)BN * 32768;
    float* out2 = out1 + (size_t)BN * 8192;

    k_prep<<<5, 256, 0, stream>>>(Wq, Wk, Wv, Wot, Wtg, Wt);
    k_main<<<BN, 256, 0, stream>>>(XQ, XK, Tgt, Wt, bq, bk, bv, bot, btg,
                                   g_time, b_time, g_tgt, b_tgt,
                                   out0, out1, out2);
}